// Round 10
// baseline (130.324 us; speedup 1.0000x reference)
//
#include <hip/hip_runtime.h>
#include <hip/hip_bf16.h>
#include <stdint.h>

#define N    8192
#define D    256
#define NCLS 100

static constexpr float TEMP    = 0.5f;
static constexpr float SCALE_F = 1.69864360f;  // sqrt(log2e/TEMP)
static constexpr float LN2     = 0.69314718055994531f;

// Per-band partial slots (R10): row-side slot = 4x + colquarter (0..255),
// col-side slot = 256 + 2y + rowhalf (256..383). NSLOT = 384. Buffer is
// zero-filled in normalize; dead/masked waves simply skip their stores.
#define NSLOT 384

typedef float f32x4 __attribute__((ext_vector_type(4)));
typedef long  lx2  __attribute__((ext_vector_type(2)));

__device__ __forceinline__ unsigned short f2bf(float f) {
  union { float f; unsigned int u; } x; x.f = f;
  unsigned int r = x.u + 0x7fffu + ((x.u >> 16) & 1u);
  return (unsigned short)(r >> 16);
}
__device__ __forceinline__ float bf2f(unsigned short b) {
  union { unsigned int u; float f; } x; x.u = ((unsigned int)b) << 16;
  return x.f;
}
__device__ __forceinline__ void gld16(const void* g, void* l) {
  __builtin_amdgcn_global_load_lds(
      (const __attribute__((address_space(1))) unsigned int*)g,
      (__attribute__((address_space(3))) unsigned int*)l, 16, 0, 0);
}

// fp8 fragment-PAIR-major layout: for row r, k:
//   kq = k>>6, kl = k&63, kkl = kl>>5, q = (kl>>3)&3
//   addr = (r>>4)*4096 + kq*1024 + q*256 + (r&15)*16 + kkl*8 + (k&7)
// -> lane (quad,l15)'s fragments for BOTH kkl halves of one kq are one
//    contiguous 16B (ds_read_b128); a wave's read of one kq-panel is a
//    contiguous 1024B (conflict-free); staging is a flat contiguous copy.

// ---- Kernel A: row-normalize; bf16 row-major copy (class sums) + fp8 e4m3
// fragment-pair-major copy (GEMM); also zero-fills the partial buffer.
__global__ __launch_bounds__(256) void normalize_kernel(
    const float* __restrict__ emb, const long long* __restrict__ label,
    unsigned short* __restrict__ abf, unsigned char* __restrict__ a8,
    float* __restrict__ part, int* __restrict__ cnt, int* __restrict__ list) {
  const int row  = blockIdx.x * 4 + (threadIdx.x >> 6);
  const int lane = threadIdx.x & 63;
  const float4 v = ((const float4*)(emb + (size_t)row * D))[lane];
  float ss = v.x * v.x + v.y * v.y + v.z * v.z + v.w * v.w;
#pragma unroll
  for (int off = 1; off < 64; off <<= 1) ss += __shfl_xor(ss, off);
  const float s = rsqrtf(ss) * SCALE_F;
  const float x = v.x * s, y = v.y * s, z = v.z * s, wv = v.w * s;

  ushort4 o;
  o.x = f2bf(x); o.y = f2bf(y); o.z = f2bf(z); o.w = f2bf(wv);
  ((ushort4*)(abf + (size_t)row * D))[lane] = o;

  int p = __builtin_amdgcn_cvt_pk_fp8_f32(x, y, 0, false);
  p = __builtin_amdgcn_cvt_pk_fp8_f32(z, wv, p, true);
  // k0 = lane*4: kq=lane>>4, q=(lane>>1)&3, kkl=(lane>>3)&1, k&7=(lane&1)*4
  *(int*)(a8 + (size_t)(row >> 4) * 4096 + (lane >> 4) * 1024 +
          ((lane >> 1) & 3) * 256 + (row & 15) * 16 + ((lane >> 3) & 1) * 8 +
          (lane & 1) * 4) = p;

  // Zero-fill part: 64*384*128 = 3,145,728 floats = exactly 6 per thread
  // across the 2048x256 grid, coalesced.
  const int gtid = blockIdx.x * 256 + threadIdx.x;
#pragma unroll
  for (int k = 0; k < 6; ++k) part[(size_t)k * 524288 + gtid] = 0.f;

  if (lane == 0) {
    const int c = (int)label[row];
    const int slot = atomicAdd(cnt + c, 1);
    list[c * 256 + slot] = row;
  }
}

struct TileCoord { int x, y; };
__device__ __forceinline__ TileCoord tri_decode(int b) {
  int x = (int)((-1.0f + sqrtf(1.0f + 8.0f * (float)b)) * 0.5f);
  while ((x + 1) * (x + 2) / 2 <= b) ++x;
  while (x * (x + 1) / 2 > b) --x;
  return {x, b - x * (x + 1) / 2};
}

// ---- Kernel B: symmetric (strict upper triangle), one block per live
// 128x128 sub-tile (2080 blocks).
//
// R10 change (wave-count fix): every variant since R3 ran at 2 waves/SIMD
// (64KB LDS -> 2 blocks/CU at 4 waves, or 220 VGPR -> 2 waves/SIMD), and
// every one stalled at ~30 us vs the 8.5 us MFMA floor with MfmaUtil
// 13-35%. The MFMA ubenches saturate at >=4 waves/SIMD. Now the SAME
// 128x128 tile is split across 8 waves (512 threads): wave w owns a
// 64x32 sub-tile (acc = 32 VGPR, A 4 panels + B 2 panels from LDS),
// est. ~110 VGPR, launch_bounds(512,4) caps at 128 -> 4 waves/SIMD,
// 16 waves/CU, 2 blocks/CU (64 KB LDS). Single staging drain as R6.
__global__ __launch_bounds__(512, 4) void simexp_rowsum_kernel(
    const unsigned char* __restrict__ A, float* __restrict__ part) {
  __shared__ __align__(16) unsigned char sa[128 * 256];  // 32 KB A tile
  __shared__ __align__(16) unsigned char sb[128 * 256];  // 32 KB B tile
  const int tid  = threadIdx.x;
  const int w    = tid >> 6;   // 0..7
  const int lane = tid & 63;
  const int quad = lane >> 4;
  const int l15  = lane & 15;

  const TileCoord tc = tri_decode(blockIdx.x);
  const int x = tc.x, y = tc.y;
  const int row0 = y << 7;
  const int col0 = x << 7;
  const bool diag = (x == y);
  const int wm  = (w & 1) * 64;   // wave's row half: 0 or 64
  const int jqi = w >> 1;         // wave's col quarter: 0..3
  const int jq  = jqi * 32;

  // Stage A and B tiles (32 KB each, flat contiguous): 32 segs of 1024 B
  // per tile; wave w stages segs w*4..w*4+3 of both. Single drain.
#pragma unroll
  for (int p = 0; p < 4; ++p) {
    const int seg = w * 4 + p;  // wave-uniform
    gld16(A + (size_t)(row0 >> 4) * 4096 + seg * 1024 + lane * 16,
          sa + seg * 1024);
    gld16(A + (size_t)(col0 >> 4) * 4096 + seg * 1024 + lane * 16,
          sb + seg * 1024);
  }
  __syncthreads();  // the only barrier (implicit vmcnt(0) drain)

  // Diagonal block, wave region entirely strictly-lower: nothing to do
  // (its partial slots stay zero from the pre-fill).
  if (diag && jq + 32 <= wm) return;
  const bool needmask = diag && (jq < wm + 64);  // region straddles diagonal

  const int pam = (w & 1) * 4;  // A panel base (wave's 64 rows)
  const int pbn = jqi * 2;      // B panel base (wave's 32 cols)
  const int lo  = quad * 256 + l15 * 16;

  f32x4 acc[4][2];
#pragma unroll
  for (int mt = 0; mt < 4; ++mt)
#pragma unroll
    for (int nt = 0; nt < 2; ++nt) acc[mt][nt] = (f32x4){0.f, 0.f, 0.f, 0.f};

#pragma unroll
  for (int kq = 0; kq < 4; ++kq) {
    lx2 aF[4], bF[2];
#pragma unroll
    for (int mt = 0; mt < 4; ++mt)
      aF[mt] = *(const lx2*)(sa + (pam + mt) * 4096 + kq * 1024 + lo);
#pragma unroll
    for (int nt = 0; nt < 2; ++nt)
      bF[nt] = *(const lx2*)(sb + (pbn + nt) * 4096 + kq * 1024 + lo);
#pragma unroll
    for (int kkl = 0; kkl < 2; ++kkl)
#pragma unroll
      for (int mt = 0; mt < 4; ++mt)
#pragma unroll
        for (int nt = 0; nt < 2; ++nt)
          acc[mt][nt] = __builtin_amdgcn_mfma_f32_16x16x32_fp8_fp8(
              aF[mt][kkl], bF[nt][kkl], acc[mt][nt], 0, 0, 0);
  }

  // Epilogue: exp2, diagonal mask, row partials + column partials.
  float rowpart[4][4];
  float colpart[2] = {0.f, 0.f};
#pragma unroll
  for (int mt = 0; mt < 4; ++mt)
#pragma unroll
    for (int e = 0; e < 4; ++e) rowpart[mt][e] = 0.f;
#pragma unroll
  for (int mt = 0; mt < 4; ++mt)
#pragma unroll
    for (int nt = 0; nt < 2; ++nt)
#pragma unroll
      for (int e = 0; e < 4; ++e) {
        float v = __builtin_amdgcn_exp2f(acc[mt][nt][e]);
        if (needmask) {
          const int iw = wm + mt * 16 + quad * 4 + e;  // local row
          const int jw = jq + nt * 16 + l15;           // local col
          v = (iw < jw) ? v : 0.f;
        }
        rowpart[mt][e] += v;
        colpart[nt] += v;
      }

  // Partial destinations (plain stores, zero-filled buffer, bijective).
  float* rowdst = part + ((size_t)y * NSLOT + 4 * x + jqi) * 128 + wm;
  float* coldst = part + ((size_t)x * NSLOT + 256 + 2 * y + (w & 1)) * 128 + jq;

  // Column reduce over the wave's 64 rows (lane bits 4,5).
#pragma unroll
  for (int nt = 0; nt < 2; ++nt) {
    float v = colpart[nt];
    v += __shfl_xor(v, 16);
    v += __shfl_xor(v, 32);
    if (quad == 0) coldst[nt * 16 + l15] = v;
  }
  // Row reduce over the wave's 32 cols (lane bits 0..3).
#pragma unroll
  for (int mt = 0; mt < 4; ++mt)
#pragma unroll
    for (int e = 0; e < 4; ++e) {
      float v = rowpart[mt][e];
      v += __shfl_xor(v, 1);
      v += __shfl_xor(v, 2);
      v += __shfl_xor(v, 4);
      v += __shfl_xor(v, 8);
      if (l15 == 0) rowdst[mt * 16 + quad * 4 + e] = v;
    }
}

__global__ __launch_bounds__(256) void finalize_kernel(
    const unsigned short* __restrict__ abf, const float* __restrict__ part,
    const long long* __restrict__ label, const int* __restrict__ cnt,
    const int* __restrict__ list, float* __restrict__ out) {
  __shared__ float red[4];
  __shared__ int rows_l[256];
  const int tid  = threadIdx.x;
  const int w    = tid >> 6;
  const int lane = tid & 63;

  if (blockIdx.x < NCLS) {
    const int c = blockIdx.x;
    const int m = cnt[c];
    if (m <= 1) return;
    if (tid < m) rows_l[tid] = list[c * 256 + tid];
    __syncthreads();
    float acc = 0.f;
    for (int s = 0; s < m; ++s)
      acc += bf2f(abf[(size_t)rows_l[s] * D + tid]);
    float v = acc * acc;
#pragma unroll
    for (int off = 1; off < 64; off <<= 1) v += __shfl_xor(v, off);
    if (lane == 0) red[w] = v;
    __syncthreads();
    if (tid == 0) {
      const float ssq = red[0] + red[1] + red[2] + red[3];
      const float term = (ssq * LN2 - 2.0f * (float)m) / (float)(m - 1);
      atomicAdd(out, -term);
    }
  } else {
    // rowsum_i = sum of the 384 per-block partials for this row's band.
    const int i = (blockIdx.x - NCLS) * 256 + tid;
    const int band = i >> 7, r = i & 127;
    const float* ps = part + (size_t)band * NSLOT * 128 + r;
    float rs = 0.f;
#pragma unroll 16
    for (int s = 0; s < NSLOT; ++s) rs += ps[(size_t)s * 128];
    const int c = (int)label[i];
    float v = 0.f;
    if (cnt[c] > 1)
      v = __builtin_amdgcn_logf(rs) * LN2;
#pragma unroll
    for (int off = 1; off < 64; off <<= 1) v += __shfl_xor(v, off);
    if (lane == 0) red[w] = v;
    __syncthreads();
    if (tid == 0)
      atomicAdd(out, red[0] + red[1] + red[2] + red[3]);
  }
}

extern "C" void kernel_launch(void* const* d_in, const int* in_sizes, int n_in,
                              void* d_out, int out_size, void* d_ws,
                              size_t ws_size, hipStream_t stream) {
  const float* emb = (const float*)d_in[0];
  const long long* label = (const long long*)d_in[1];
  float* out = (float*)d_out;

  char* ws = (char*)d_ws;
  unsigned short* abf = (unsigned short*)ws;            // 4 MB bf16 row-major
  unsigned char* a8 = (unsigned char*)(ws + (size_t)N * D * 2);  // 2 MB fp8
  float* part = (float*)(ws + (size_t)N * D * 3);       // 64*384*128 f32
  int* cnt = (int*)(ws + (size_t)N * D * 3 + (size_t)64 * NSLOT * 128 * 4);
  int* list = cnt + 128;                                // NCLS*256 ints

  hipMemsetAsync(cnt, 0, 128 * 4, stream);
  hipMemsetAsync(out, 0, sizeof(float), stream);

  normalize_kernel<<<N / 4, 256, 0, stream>>>(emb, label, abf, a8, part, cnt,
                                              list);

  // One block per live upper-triangle 128x128 sub-tile: 64*65/2 = 2080.
  simexp_rowsum_kernel<<<2080, 512, 0, stream>>>(a8, part);

  finalize_kernel<<<NCLS + N / 256, 256, 0, stream>>>(abf, part, label, cnt,
                                                      list, out);
}